// Round 4
// baseline (120.691 us; speedup 1.0000x reference)
//
#include <hip/hip_runtime.h>

// MedianFilter1D: x[16,64,16384] fp32, k=9, zero-pad 4 each side, lower median.
// Memory-bound: 128 MiB compulsory HBM traffic -> ~20.4us kernel floor @6.3TB/s.
// R4: exactly-once input reads. Each thread NT-loads its own 2 float4s
// (8 outputs); halos come from neighbor lanes via shuffle (wave covers 512
// contiguous elements; 16384 % 512 == 0 so row edges == wave edges; only
// lanes 0/63 do a guarded halo load). NT loads+stores bypass L2 (streams,
// zero reuse). Saves 1/3 of VMEM issue vs R3.

#define L_ROW  16384
#define L_MASK 16383

typedef float v4f __attribute__((ext_vector_type(4)));

__device__ __forceinline__ void s2(float &a, float &b) {
    float lo = fminf(a, b);
    float hi = fmaxf(a, b);
    a = lo; b = hi;
}

// Paeth's 19-CE median-of-9 network; returns the element at sorted pos 4.
__device__ __forceinline__ float med9(float p0, float p1, float p2, float p3,
                                      float p4, float p5, float p6, float p7,
                                      float p8) {
    s2(p1, p2); s2(p4, p5); s2(p7, p8);
    s2(p0, p1); s2(p3, p4); s2(p6, p7);
    s2(p1, p2); s2(p4, p5); s2(p7, p8);
    s2(p0, p3); s2(p5, p8); s2(p4, p7);
    s2(p3, p6); s2(p1, p4); s2(p2, p5);
    s2(p4, p7); s2(p4, p2); s2(p6, p4);
    s2(p4, p2);
    return p4;
}

__device__ __forceinline__ v4f shfl_up1(v4f v) {
    v4f r;
    r.x = __shfl_up(v.x, 1);
    r.y = __shfl_up(v.y, 1);
    r.z = __shfl_up(v.z, 1);
    r.w = __shfl_up(v.w, 1);
    return r;
}

__device__ __forceinline__ v4f shfl_down1(v4f v) {
    v4f r;
    r.x = __shfl_down(v.x, 1);
    r.y = __shfl_down(v.y, 1);
    r.z = __shfl_down(v.z, 1);
    r.w = __shfl_down(v.w, 1);
    return r;
}

__global__ __launch_bounds__(256, 4)
void MedianFilter1D_66924180406949_kernel(const float* __restrict__ x,
                                          float* __restrict__ y) {
    const int tid  = blockIdx.x * 256 + threadIdx.x;  // 8-element group index
    const int v    = tid << 1;                        // base float4 index
    const int pos  = tid << 3;                        // element index (flat)
    const int inrow = pos & L_MASK;                   // position within row
    const int lane = threadIdx.x & 63;

    const v4f* __restrict__ xv = (const v4f*)x;

    // Own data: elements [pos .. pos+7], read exactly once -> nontemporal.
    v4f B0 = __builtin_nontemporal_load(&xv[v]);
    v4f B1 = __builtin_nontemporal_load(&xv[v + 1]);

    // Halos from neighbor lanes (wave covers 512 contiguous elements).
    v4f A = shfl_up1(B1);     // prev thread's B1 = elements [pos-4 .. pos-1]
    v4f C = shfl_down1(B0);   // next thread's B0 = elements [pos+8 .. pos+11]

    if (lane == 0) {          // wave left edge: real load or row zero-pad
        A = (inrow == 0) ? (v4f){0.f, 0.f, 0.f, 0.f} : xv[v - 1];
    }
    if (lane == 63) {         // wave right edge: real load or row zero-pad
        C = (inrow == (L_ROW - 8)) ? (v4f){0.f, 0.f, 0.f, 0.f} : xv[v + 2];
    }

    const float w0 = A.x,  w1 = A.y,  w2 = A.z,  w3 = A.w;
    const float w4 = B0.x, w5 = B0.y, w6 = B0.z, w7 = B0.w;
    const float w8 = B1.x, w9 = B1.y, w10 = B1.z, w11 = B1.w;
    const float w12 = C.x, w13 = C.y, w14 = C.z, w15 = C.w;

    v4f o0, o1;
    o0.x = med9(w0, w1, w2,  w3,  w4,  w5,  w6,  w7,  w8);
    o0.y = med9(w1, w2, w3,  w4,  w5,  w6,  w7,  w8,  w9);
    o0.z = med9(w2, w3, w4,  w5,  w6,  w7,  w8,  w9,  w10);
    o0.w = med9(w3, w4, w5,  w6,  w7,  w8,  w9,  w10, w11);
    o1.x = med9(w4, w5, w6,  w7,  w8,  w9,  w10, w11, w12);
    o1.y = med9(w5, w6, w7,  w8,  w9,  w10, w11, w12, w13);
    o1.z = med9(w6, w7, w8,  w9,  w10, w11, w12, w13, w14);
    o1.w = med9(w7, w8, w9,  w10, w11, w12, w13, w14, w15);

    v4f* __restrict__ yv = (v4f*)y;
    __builtin_nontemporal_store(o0, &yv[v]);
    __builtin_nontemporal_store(o1, &yv[v + 1]);
}

extern "C" void kernel_launch(void* const* d_in, const int* in_sizes, int n_in,
                              void* d_out, int out_size, void* d_ws, size_t ws_size,
                              hipStream_t stream) {
    const float* x = (const float*)d_in[0];
    float* y = (float*)d_out;
    const int total = in_sizes[0];          // 16 * 64 * 16384 = 16777216
    const int threads = total / 8;          // one 8-element group per thread
    const int blocks = threads / 256;       // 8192 blocks
    MedianFilter1D_66924180406949_kernel<<<blocks, 256, 0, stream>>>(x, y);
}